// Round 15
// baseline (239.584 us; speedup 1.0000x reference)
//
#include <hip/hip_runtime.h>
#include <hip/hip_bf16.h>
#include <cstdint>
#include <cstddef>

// Problem constants
#define B_    16
#define CIN   960
#define HH    56
#define WW_   56
#define GG    2
#define COUT  96
#define NK_   5
#define PIX   3136   // 56*56
#define NCH   30     // K-chunks of 32

// Workspace layout (float indices):
//   wf   bf16 fragment-ordered, PADDED: [NCH][8192 B]
//   bias f32[96] at 61440
//   y    bf16[16][96][3136] at 61568            (2,408,448 floats)
//   xb16 bf16[16][960][3136] at 2470016         (24,084,480 floats) ~96 MB
#define WF_OFF   0
#define BIAS_OFF 61440
#define Y_OFF    61568
#define XB_OFF   2470016

typedef __attribute__((ext_vector_type(8))) short bf16x8;
typedef __attribute__((ext_vector_type(4))) float f32x4;

__device__ __forceinline__ short f2b(float f) {
    union { float f; unsigned u; } c; c.f = f;
    unsigned r = (c.u + 0x7FFFu + ((c.u >> 16) & 1u)) >> 16;
    return (short)r;
}
__device__ __forceinline__ float b2f(short s) {
    union { unsigned u; float f; } c;
    c.u = ((unsigned)(unsigned short)s) << 16;
    return c.f;
}

#define GLOAD_LDS16(gp, lp)                                                        \
    __builtin_amdgcn_global_load_lds(                                              \
        (const __attribute__((address_space(1))) unsigned*)(gp),                   \
        (__attribute__((address_space(3))) unsigned*)(lp), 16, 0, 0)

// ---------------------------------------------------------------------------
// K0a: fragment-ordered weights, padded per chunk (identical to 93.5 build).
__global__ void prep_wb(const float* __restrict__ pw, const float* __restrict__ sc,
                        short* __restrict__ wf) {
    int idx = blockIdx.x * 256 + threadIdx.x;   // (n*6+f)*64 + lane
    if (idx >= NCH * 6 * 64) return;
    const int lane = idx & 63;
    const int nf   = idx >> 6;
    const int f    = nf % 6;
    const int n    = nf / 6;
    const int o    = f * 16 + (lane & 15);
    const int c0   = n * 32 + (lane >> 4) * 8;
    bf16x8 v;
#pragma unroll
    for (int k = 0; k < 8; ++k)
        v[k] = f2b(pw[o * CIN + c0 + k] * (sc[c0 + k] + 1e-5f));
    *(bf16x8*)((char*)wf + (size_t)n * 8192 + (f * 64 + lane) * 16) = v;
}

// bias_o[o] = sum_c proj_w[o][c] * local_bias[c]   (96 blocks x 1 wave)
__global__ void prep_bias(const float* __restrict__ pw, const float* __restrict__ bi,
                          float* __restrict__ bias) {
    const int o = blockIdx.x;
    const int l = threadIdx.x;
    float s = 0.f;
    for (int c = l; c < CIN; c += 64) s += pw[o * CIN + c] * bi[c];
#pragma unroll
    for (int off = 32; off; off >>= 1) s += __shfl_down(s, off);
    if (l == 0) bias[o] = s;
}

// ---------------------------------------------------------------------------
// K1: y[b,o,px] = sum_c W[o][c]*x[b,c,px]   (bias in finalize; y bf16)
// EXACT round-8 (93.5us) pipeline: 3-buf x + 3-buf W, raw s_barrier, counted
// vmcnt; PLUS: each wave persists its B-fragment as bf16 to xb16 (px-major)
// with 4 asm global_store_short per chunk (k-range split by m: all 8 waves
// store, ledger uniform). finalize then gathers from xb16 (96 MB vs 192).
// vmcnt ledger (in-order retirement; region(n) = [stage(n+2) x2, st x4]):
//   STEP0: vmcnt(2), STEP1: vmcnt(6), STEP2..28: vmcnt(10), STEP29: vmcnt(8).
__global__ __launch_bounds__(512)
void conv_mfma(const float* __restrict__ x, const short* __restrict__ wf,
               short* __restrict__ yb, short* __restrict__ xb) {
    const int tid  = threadIdx.x;
    const int lane = tid & 63;
    const int wv   = tid >> 6;          // 0..7
    const int m    = wv >> 2;           // o-half
    const int n    = wv & 3;            // px tile
    const int b    = blockIdx.y;
    const int px0  = blockIdx.x * 64;

    __shared__ __align__(16) char xsb[3 * 8192];   // x chunks [32ch][64px] f32
    __shared__ __align__(16) char wlb[3 * 8192];   // W chunks (6 frags + pad)

    const float* xbase = x + (size_t)b * CIN * PIX + px0;
    const char*  wfB   = (const char*)wf;

    // staging constants (one x-DMA + one W-DMA per wave per chunk)
    const int sch  = wv * 4 + (lane >> 4);               // channel within chunk
    const int sS   = (wv >> 1) & 3;                      // == (sch>>3)&3
    const int soff = (((lane >> 2) & 3) ^ sS) * 16 + (lane & 3) * 4;  // src px (floats)
    const int wsub = wv * 1024 + lane * 16;              // W copy offset (bytes)

    // compute constants
    const int kb    = lane >> 4;
    const int bcol  = (lane & 15) * 4;
    const int bslot = ((n ^ kb) & 3) * 64;
    const int babs  = kb * 2048 + bslot + bcol;          // + k*256, + BI*8192
    const int abase = m * 3072 + lane * 16;              // + f*1024, + BI*8192

    // bf16-x persist base: this wave's pixel column (px-major layout)
    short* const xstb = xb + (size_t)b * CIN * PIX + px0 + n * 16 + (lane & 15);
    const int mk4 = m * 4;

    f32x4 acc0 = {0.f, 0.f, 0.f, 0.f};
    f32x4 acc1 = {0.f, 0.f, 0.f, 0.f};
    f32x4 acc2 = {0.f, 0.f, 0.f, 0.f};

#define STAGE(BS, c0)                                                            \
    {                                                                            \
        GLOAD_LDS16(xbase + (size_t)((c0) + sch) * PIX + soff,                   \
                    xsb + (BS) * 8192 + wv * 1024);                              \
        GLOAD_LDS16(wfB + (size_t)((c0) >> 5) * 8192 + wsub,                     \
                    wlb + (BS) * 8192 + wv * 1024);                              \
    }

    // prologue: chunks 0,1 in flight (4 VMEM/wave)
    STAGE(0, 0);
    STAGE(1, 32);

    // STEP(n): wait vmcnt(VM) [retires stage(n)] -> barrier -> frag reads ->
    //          prefetch stage(n+2) -> persist 4 bf16 x-shorts -> 3 MFMA.
#define STEP(n_, BI, BS, VM)                                                     \
    {                                                                            \
        asm volatile("s_waitcnt vmcnt(" #VM ")" ::: "memory");                   \
        asm volatile("s_barrier" ::: "memory");                                  \
        bf16x8 bfrag;                                                            \
        _Pragma("unroll")                                                        \
        for (int k = 0; k < 8; ++k)                                              \
            bfrag[k] = f2b(*(const float*)(xsb + (BI) * 8192 + babs + k * 256)); \
        const bf16x8 af0 = *(const bf16x8*)(wlb + (BI) * 8192 + abase);          \
        const bf16x8 af1 = *(const bf16x8*)(wlb + (BI) * 8192 + abase + 1024);   \
        const bf16x8 af2 = *(const bf16x8*)(wlb + (BI) * 8192 + abase + 2048);   \
        if ((n_) + 2 < NCH) STAGE(BS, ((n_) + 2) * 32);                          \
        _Pragma("unroll")                                                        \
        for (int j = 0; j < 4; ++j) {                                            \
            const short dj = (m == 0) ? bfrag[j] : bfrag[4 + j];                 \
            short* sp = xstb + (size_t)((n_) * 32 + kb * 8 + mk4 + j) * PIX;     \
            asm volatile("global_store_short %0, %1, off"                        \
                         :: "v"(sp), "v"((unsigned)(unsigned short)dj)           \
                         : "memory");                                            \
        }                                                                        \
        acc0 = __builtin_amdgcn_mfma_f32_16x16x32_bf16(af0, bfrag, acc0, 0,0,0); \
        acc1 = __builtin_amdgcn_mfma_f32_16x16x32_bf16(af1, bfrag, acc1, 0,0,0); \
        acc2 = __builtin_amdgcn_mfma_f32_16x16x32_bf16(af2, bfrag, acc2, 0,0,0); \
    }

    STEP(0, 0, 2, 2);
    STEP(1, 1, 0, 6);
#pragma unroll 1
    for (int mm = 0; mm < 9; ++mm) {
        const int n0 = 2 + mm * 3;
        STEP(n0 + 0, 2, 1, 10);
        STEP(n0 + 1, 0, 2, 10);
        STEP(n0 + 2, 1, 0, 10);
    }
    STEP(29, 2, 1, 8);   // drain stage(29); st(27)/st(28) may remain in flight
#undef STEP
#undef STAGE

    // epilogue: C/D col(px) = lane&15, row(o) = (lane>>4)*4 + r
    short* yp = yb + (size_t)b * COUT * PIX + px0 + n * 16 + (lane & 15);
    const int o0 = m * 48 + (lane >> 4) * 4;
#pragma unroll
    for (int r = 0; r < 4; ++r) yp[(size_t)(o0 +      r) * PIX] = f2b(acc0[r]);
#pragma unroll
    for (int r = 0; r < 4; ++r) yp[(size_t)(o0 + 16 + r) * PIX] = f2b(acc1[r]);
#pragma unroll
    for (int r = 0; r < 4; ++r) yp[(size_t)(o0 + 32 + r) * PIX] = f2b(acc2[r]);
}

// ---------------------------------------------------------------------------
// Antialiased 58->56 triangle weights; tap indices mapped to the 56-grid.
__device__ __forceinline__ void rweights56(int o, short* idx, float* wt) {
    const float ratio = 58.0f / 56.0f;
    const float kinv  = 56.0f / 58.0f;
    const float sf = ((float)o + 0.5f) * ratio - 0.5f;
    const int f0 = (int)floorf(sf);
    float sum = 0.f;
#pragma unroll
    for (int t = 0; t < 4; ++t) {
        int i = f0 - 1 + t;
        float w = fmaxf(1.0f - fabsf(sf - (float)i) * kinv, 0.0f);
        if (i < 0 || i > 57) w = 0.0f;
        idx[t] = (short)min(HH - 1, max(0, i - 1));
        wt[t] = w;
        sum += w;
    }
    const float inv = 1.0f / sum;
#pragma unroll
    for (int t = 0; t < 4; ++t) wt[t] *= inv;
}

// ---------------------------------------------------------------------------
// K2: round-8 finalize structure, but gather taps read bf16 xb16 (half bytes).
__global__ __launch_bounds__(256)
void finalize(const short* __restrict__ xb, const int* __restrict__ pad_hv,
              const int* __restrict__ idt, const short* __restrict__ yb,
              const float* __restrict__ bias, const float* __restrict__ alpha_p,
              float* __restrict__ out) {
    const int bc = blockIdx.x;          // b*96 + co
    const int co = bc % COUT;
    const int b  = bc / COUT;
    const int t  = threadIdx.x;

    __shared__ float  ylds[PIX];
    __shared__ float4 wt4[56];
    __shared__ short4 id4[56];
    __shared__ int   ish[10], isv[10], ipl[10];
    __shared__ float fid[10];

    if (t < 10) {
        const int g = t / 5;
        const int k = t - g * 5;
        const int slot = co * NK_ + k;
        ish[t] = pad_hv[slot * 4 + g];
        isv[t] = pad_hv[slot * 4 + 2 + g];
        fid[t] = (idt[slot * 2 + g] >= 0) ? 1.f : 0.f;
        ipl[t] = (g * (COUT * NK_) + slot) * PIX;
    }
    if (t < 56) {
        short ii[4]; float ww[4];
        rweights56(t, ii, ww);
        wt4[t] = make_float4(ww[0], ww[1], ww[2], ww[3]);
        id4[t] = make_short4(ii[0], ii[1], ii[2], ii[3]);
    }
    {   // stage y plane as f32
        const short* yp = yb + (size_t)bc * PIX;
#pragma unroll 1
        for (int i = t; i < PIX / 4; i += 256) {
            const short4 s4 = *(const short4*)(yp + i * 4);
            *(float4*)(ylds + i * 4) =
                make_float4(b2f(s4.x), b2f(s4.y), b2f(s4.z), b2f(s4.w));
        }
    }
    __syncthreads();

    int   ish_r[10], isv_r[10], ipl_r[10];
    float fid_r[10];
#pragma unroll
    for (int p = 0; p < 10; ++p) {
        ish_r[p] = ish[p]; isv_r[p] = isv[p];
        ipl_r[p] = ipl[p]; fid_r[p] = fid[p];
    }

    const float alpha = alpha_p[0];
    const float ia    = 1.0f - alpha;
    const float bco   = bias[co];
    const short* xbb = xb + (size_t)b * CIN * PIX;
    float* op = out + (size_t)bc * PIX;

#pragma unroll 1
    for (int px = t; px < PIX; px += 256) {
        const int h = (px * 18725) >> 20;
        const int w = px - h * WW_;
        const int hrow = px - w;

        float accg = 0.f;
#pragma unroll
        for (int p = 0; p < 10; ++p) {
            const short* xc = xbb + ipl_r[p];
            const int jw = w + ish_r[p];
            const float mh = (jw >= -1 && jw <= WW_) ? 1.f : 0.f;
            accg += mh * b2f(xc[hrow + min(WW_ - 1, max(0, jw))]);

            const int iv = h + isv_r[p];
            const float mv = (iv >= -1 && iv <= HH) ? 1.f : 0.f;
            accg += mv * b2f(xc[min(HH - 1, max(0, iv)) * WW_ + w]);

            accg += fid_r[p] * b2f(xc[px]);
        }

        const float4 ww4 = wt4[w];
        const short4 iw4 = id4[w];
        const float4 wh4 = wt4[h];
        const short4 ih4 = id4[h];
        float accl = 0.f;
#pragma unroll
        for (int a = 0; a < 4; ++a) {
            const int row = ((const short*)&ih4)[a] * WW_;
            const float* yr = ylds + row;
            float rs;
            rs = ww4.x * yr[iw4.x];
            rs = fmaf(ww4.y, yr[iw4.y], rs);
            rs = fmaf(ww4.z, yr[iw4.z], rs);
            rs = fmaf(ww4.w, yr[iw4.w], rs);
            accl = fmaf(((const float*)&wh4)[a], rs, accl);
        }
        accl += bco;

        op[px] = alpha * accg * (1.0f / 3.0f) + ia * accl;
    }
}

// ---------------------------------------------------------------------------
extern "C" void kernel_launch(void* const* d_in, const int* in_sizes, int n_in,
                              void* d_out, int out_size, void* d_ws, size_t ws_size,
                              hipStream_t stream) {
    const float* x      = (const float*)d_in[0];
    const int*   pad_hv = (const int*)d_in[1];
    const int*   idt    = (const int*)d_in[2];
    const float* lsc    = (const float*)d_in[3];
    const float* lbi    = (const float*)d_in[4];
    const float* pw     = (const float*)d_in[5];
    const float* alpha  = (const float*)d_in[6];
    float* out = (float*)d_out;

    float* ws   = (float*)d_ws;
    short* wf   = (short*)(ws + WF_OFF);
    float* bias = ws + BIAS_OFF;
    short* yb   = (short*)(ws + Y_OFF);
    short* xb16 = (short*)(ws + XB_OFF);

    prep_wb<<<(NCH * 6 * 64 + 255) / 256, 256, 0, stream>>>(pw, lsc, wf);
    prep_bias<<<COUT, 64, 0, stream>>>(pw, lbi, bias);
    conv_mfma<<<dim3(PIX / 64, B_), 512, 0, stream>>>(x, wf, yb, xb16);
    finalize<<<B_ * COUT, 256, 0, stream>>>(xb16, pad_hv, idt, yb, bias, alpha, out);
}

// Round 16
// 95.415 us; speedup vs baseline: 2.5110x; 2.5110x over previous
//
#include <hip/hip_runtime.h>
#include <hip/hip_bf16.h>
#include <cstdint>
#include <cstddef>

// Problem constants
#define B_    16
#define CIN   960
#define HH    56
#define WW_   56
#define GG    2
#define COUT  96
#define NK_   5
#define PIX   3136   // 56*56
#define NCH   30     // K-chunks of 32 total
#define NCHH  15     // chunks per K-half block

// Workspace layout (float indices):
//   wf   bf16 fragment-ordered, PADDED: [NCH][8192 B]  (61440 floats)
//   bias f32[96] at 61440
//   y0   bf16[16][96][3136] at 61568      (2,408,448 floats)
//   y1   bf16[16][96][3136] at 2470016
#define WF_OFF   0
#define BIAS_OFF 61440
#define Y0_OFF   61568
#define Y1_OFF   2470016

typedef __attribute__((ext_vector_type(8))) short bf16x8;
typedef __attribute__((ext_vector_type(4))) float f32x4;

__device__ __forceinline__ short f2b(float f) {
    union { float f; unsigned u; } c; c.f = f;
    unsigned r = (c.u + 0x7FFFu + ((c.u >> 16) & 1u)) >> 16;
    return (short)r;
}
__device__ __forceinline__ float b2f(short s) {
    union { unsigned u; float f; } c;
    c.u = ((unsigned)(unsigned short)s) << 16;
    return c.f;
}

#define GLOAD_LDS16(gp, lp)                                                        \
    __builtin_amdgcn_global_load_lds(                                              \
        (const __attribute__((address_space(1))) unsigned*)(gp),                   \
        (__attribute__((address_space(3))) unsigned*)(lp), 16, 0, 0)

// ---------------------------------------------------------------------------
// K0a: fragment-ordered weights, padded per chunk (identical to 93.5 build).
__global__ void prep_wb(const float* __restrict__ pw, const float* __restrict__ sc,
                        short* __restrict__ wf) {
    int idx = blockIdx.x * 256 + threadIdx.x;   // (n*6+f)*64 + lane
    if (idx >= NCH * 6 * 64) return;
    const int lane = idx & 63;
    const int nf   = idx >> 6;
    const int f    = nf % 6;
    const int n    = nf / 6;
    const int o    = f * 16 + (lane & 15);
    const int c0   = n * 32 + (lane >> 4) * 8;
    bf16x8 v;
#pragma unroll
    for (int k = 0; k < 8; ++k)
        v[k] = f2b(pw[o * CIN + c0 + k] * (sc[c0 + k] + 1e-5f));
    *(bf16x8*)((char*)wf + (size_t)n * 8192 + (f * 64 + lane) * 16) = v;
}

// bias_o[o] = sum_c proj_w[o][c] * local_bias[c]   (96 blocks x 1 wave)
__global__ void prep_bias(const float* __restrict__ pw, const float* __restrict__ bi,
                          float* __restrict__ bias) {
    const int o = blockIdx.x;
    const int l = threadIdx.x;
    float s = 0.f;
    for (int c = l; c < CIN; c += 64) s += pw[o * CIN + c] * bi[c];
#pragma unroll
    for (int off = 32; off; off >>= 1) s += __shfl_down(s, off);
    if (l == 0) bias[o] = s;
}

// ---------------------------------------------------------------------------
// K1: K-SPLIT GEMM. Block (px-tile, b, z) computes the partial sum over
// channels [z*480, z*480+480) and writes bf16 partial y_z. Grid = 49*16*2 =
// 1568 blocks -> 6.1/CU, filling the 4-block/CU LDS capacity (40 KB:
// x 3-buf + W 2-buf). Pipeline identical to the proven r8/r14 build:
// raw s_barrier, counted vmcnt, x distance-2, W distance-1.
// vmcnt ledger (per wave; issues post-barrier, W before x):
//   prologue: x(0), W(0), x(1)
//   STEP(n<=13): wait vmcnt(1) [retire x(n),W(n)], barrier, frag reads,
//                issue W(n+1), x(n+2 if <15), 3 MFMA.
//   STEP(14): vmcnt(0), no issues.
// W(n+1) lands in the buffer read at step n-1; those ds_reads retire before
// each wave's step-(n-1) MFMAs issue, which precede barrier n. Safe.
__global__ __launch_bounds__(512)
void conv_mfma(const float* __restrict__ x, const short* __restrict__ wf,
               short* __restrict__ yb0, short* __restrict__ yb1) {
    const int tid  = threadIdx.x;
    const int lane = tid & 63;
    const int wv   = tid >> 6;          // 0..7
    const int m    = wv >> 2;           // o-half
    const int n    = wv & 3;            // px tile
    const int b    = blockIdx.y;
    const int z    = blockIdx.z;        // K-half
    const int px0  = blockIdx.x * 64;

    __shared__ __align__(16) char xsb[3 * 8192];   // x chunks [32ch][64px] f32
    __shared__ __align__(16) char wlb[2 * 8192];   // W chunks (6 frags + pad)

    const float* xbase = x + (size_t)b * CIN * PIX + (size_t)z * (NCHH * 32) * PIX + px0;
    const char*  wfB   = (const char*)wf + (size_t)z * NCHH * 8192;

    // staging constants (one x-DMA + one W-DMA per wave per chunk)
    const int sch  = wv * 4 + (lane >> 4);               // channel within chunk
    const int sS   = (wv >> 1) & 3;                      // == (sch>>3)&3
    const int soff = (((lane >> 2) & 3) ^ sS) * 16 + (lane & 3) * 4;  // src px (floats)
    const int wsub = wv * 1024 + lane * 16;              // W copy offset (bytes)

    // compute constants
    const int kb    = lane >> 4;
    const int bcol  = (lane & 15) * 4;
    const int bslot = ((n ^ kb) & 3) * 64;
    const int babs  = kb * 2048 + bslot + bcol;          // + k*256, + XBI*8192
    const int abase = m * 3072 + lane * 16;              // + f*1024, + WBI*8192

    f32x4 acc0 = {0.f, 0.f, 0.f, 0.f};
    f32x4 acc1 = {0.f, 0.f, 0.f, 0.f};
    f32x4 acc2 = {0.f, 0.f, 0.f, 0.f};

#define XDMA(BS, c0)                                                             \
    GLOAD_LDS16(xbase + (size_t)((c0) + sch) * PIX + soff,                       \
                xsb + (BS) * 8192 + wv * 1024);
#define WDMA(N)                                                                  \
    GLOAD_LDS16(wfB + (size_t)(N) * 8192 + wsub,                                 \
                wlb + ((N) & 1) * 8192 + wv * 1024);

    // prologue: x(0), W(0), x(1)
    XDMA(0, 0);
    WDMA(0);
    XDMA(1, 32);

#define STEP(n_, XBI, XBS, VM)                                                   \
    {                                                                            \
        asm volatile("s_waitcnt vmcnt(" #VM ")" ::: "memory");                   \
        asm volatile("s_barrier" ::: "memory");                                  \
        bf16x8 bfrag;                                                            \
        _Pragma("unroll")                                                        \
        for (int k = 0; k < 8; ++k)                                              \
            bfrag[k] = f2b(*(const float*)(xsb + (XBI) * 8192 + babs + k * 256));\
        const char* wp_ = wlb + ((n_) & 1) * 8192 + abase;                       \
        const bf16x8 af0 = *(const bf16x8*)(wp_);                                \
        const bf16x8 af1 = *(const bf16x8*)(wp_ + 1024);                         \
        const bf16x8 af2 = *(const bf16x8*)(wp_ + 2048);                         \
        if ((n_) + 1 < NCHH) WDMA((n_) + 1);                                     \
        if ((n_) + 2 < NCHH) XDMA(XBS, ((n_) + 2) * 32);                         \
        acc0 = __builtin_amdgcn_mfma_f32_16x16x32_bf16(af0, bfrag, acc0, 0,0,0); \
        acc1 = __builtin_amdgcn_mfma_f32_16x16x32_bf16(af1, bfrag, acc1, 0,0,0); \
        acc2 = __builtin_amdgcn_mfma_f32_16x16x32_bf16(af2, bfrag, acc2, 0,0,0); \
    }

#pragma unroll 1
    for (int mm = 0; mm < 4; ++mm) {
        const int n0 = mm * 3;
        STEP(n0 + 0, 0, 2, 1);
        STEP(n0 + 1, 1, 0, 1);
        STEP(n0 + 2, 2, 1, 1);
    }
    STEP(12, 0, 2, 1);
    STEP(13, 1, 0, 1);
    STEP(14, 2, 1, 0);   // drain
#undef STEP
#undef WDMA
#undef XDMA

    // epilogue: C/D col(px) = lane&15, row(o) = (lane>>4)*4 + r
    short* ybz = z ? yb1 : yb0;
    short* yp = ybz + (size_t)b * COUT * PIX + px0 + n * 16 + (lane & 15);
    const int o0 = m * 48 + (lane >> 4) * 4;
#pragma unroll
    for (int r = 0; r < 4; ++r) yp[(size_t)(o0 +      r) * PIX] = f2b(acc0[r]);
#pragma unroll
    for (int r = 0; r < 4; ++r) yp[(size_t)(o0 + 16 + r) * PIX] = f2b(acc1[r]);
#pragma unroll
    for (int r = 0; r < 4; ++r) yp[(size_t)(o0 + 32 + r) * PIX] = f2b(acc2[r]);
}

// ---------------------------------------------------------------------------
// Antialiased 58->56 triangle weights; tap indices mapped to the 56-grid.
__device__ __forceinline__ void rweights56(int o, short* idx, float* wt) {
    const float ratio = 58.0f / 56.0f;
    const float kinv  = 56.0f / 58.0f;
    const float sf = ((float)o + 0.5f) * ratio - 0.5f;
    const int f0 = (int)floorf(sf);
    float sum = 0.f;
#pragma unroll
    for (int t = 0; t < 4; ++t) {
        int i = f0 - 1 + t;
        float w = fmaxf(1.0f - fabsf(sf - (float)i) * kinv, 0.0f);
        if (i < 0 || i > 57) w = 0.0f;
        idx[t] = (short)min(HH - 1, max(0, i - 1));
        wt[t] = w;
        sum += w;
    }
    const float inv = 1.0f / sum;
#pragma unroll
    for (int t = 0; t < 4; ++t) wt[t] *= inv;
}

// ---------------------------------------------------------------------------
// K2: round-8 finalize (x gathers from the warm fp32 input), y staging now
// sums the two bf16 partials.
__global__ __launch_bounds__(256)
void finalize(const float* __restrict__ x, const int* __restrict__ pad_hv,
              const int* __restrict__ idt, const short* __restrict__ yb0,
              const short* __restrict__ yb1, const float* __restrict__ bias,
              const float* __restrict__ alpha_p, float* __restrict__ out) {
    const int bc = blockIdx.x;          // b*96 + co
    const int co = bc % COUT;
    const int b  = bc / COUT;
    const int t  = threadIdx.x;

    __shared__ float  ylds[PIX];
    __shared__ float4 wt4[56];
    __shared__ short4 id4[56];
    __shared__ int   ish[10], isv[10], ipl[10];
    __shared__ float fid[10];

    if (t < 10) {
        const int g = t / 5;
        const int k = t - g * 5;
        const int slot = co * NK_ + k;
        ish[t] = pad_hv[slot * 4 + g];
        isv[t] = pad_hv[slot * 4 + 2 + g];
        fid[t] = (idt[slot * 2 + g] >= 0) ? 1.f : 0.f;
        ipl[t] = (g * (COUT * NK_) + slot) * PIX;
    }
    if (t < 56) {
        short ii[4]; float ww[4];
        rweights56(t, ii, ww);
        wt4[t] = make_float4(ww[0], ww[1], ww[2], ww[3]);
        id4[t] = make_short4(ii[0], ii[1], ii[2], ii[3]);
    }
    {   // stage y = y0 + y1 as f32
        const short* yp0 = yb0 + (size_t)bc * PIX;
        const short* yp1 = yb1 + (size_t)bc * PIX;
#pragma unroll 1
        for (int i = t; i < PIX / 4; i += 256) {
            const short4 a = *(const short4*)(yp0 + i * 4);
            const short4 c = *(const short4*)(yp1 + i * 4);
            *(float4*)(ylds + i * 4) =
                make_float4(b2f(a.x) + b2f(c.x), b2f(a.y) + b2f(c.y),
                            b2f(a.z) + b2f(c.z), b2f(a.w) + b2f(c.w));
        }
    }
    __syncthreads();

    int   ish_r[10], isv_r[10], ipl_r[10];
    float fid_r[10];
#pragma unroll
    for (int p = 0; p < 10; ++p) {
        ish_r[p] = ish[p]; isv_r[p] = isv[p];
        ipl_r[p] = ipl[p]; fid_r[p] = fid[p];
    }

    const float alpha = alpha_p[0];
    const float ia    = 1.0f - alpha;
    const float bco   = bias[co];
    const float* xb = x + (size_t)b * CIN * PIX;
    float* op = out + (size_t)bc * PIX;

#pragma unroll 1
    for (int px = t; px < PIX; px += 256) {
        const int h = (px * 18725) >> 20;
        const int w = px - h * WW_;
        const int hrow = px - w;

        float accg = 0.f;
#pragma unroll
        for (int p = 0; p < 10; ++p) {
            const float* xc = xb + ipl_r[p];
            const int jw = w + ish_r[p];
            const float mh = (jw >= -1 && jw <= WW_) ? 1.f : 0.f;
            accg += mh * xc[hrow + min(WW_ - 1, max(0, jw))];

            const int iv = h + isv_r[p];
            const float mv = (iv >= -1 && iv <= HH) ? 1.f : 0.f;
            accg += mv * xc[min(HH - 1, max(0, iv)) * WW_ + w];

            accg += fid_r[p] * xc[px];
        }

        const float4 ww4 = wt4[w];
        const short4 iw4 = id4[w];
        const float4 wh4 = wt4[h];
        const short4 ih4 = id4[h];
        float accl = 0.f;
#pragma unroll
        for (int a = 0; a < 4; ++a) {
            const int row = ((const short*)&ih4)[a] * WW_;
            const float* yr = ylds + row;
            float rs;
            rs = ww4.x * yr[iw4.x];
            rs = fmaf(ww4.y, yr[iw4.y], rs);
            rs = fmaf(ww4.z, yr[iw4.z], rs);
            rs = fmaf(ww4.w, yr[iw4.w], rs);
            accl = fmaf(((const float*)&wh4)[a], rs, accl);
        }
        accl += bco;

        op[px] = alpha * accg * (1.0f / 3.0f) + ia * accl;
    }
}

// ---------------------------------------------------------------------------
extern "C" void kernel_launch(void* const* d_in, const int* in_sizes, int n_in,
                              void* d_out, int out_size, void* d_ws, size_t ws_size,
                              hipStream_t stream) {
    const float* x      = (const float*)d_in[0];
    const int*   pad_hv = (const int*)d_in[1];
    const int*   idt    = (const int*)d_in[2];
    const float* lsc    = (const float*)d_in[3];
    const float* lbi    = (const float*)d_in[4];
    const float* pw     = (const float*)d_in[5];
    const float* alpha  = (const float*)d_in[6];
    float* out = (float*)d_out;

    float* ws   = (float*)d_ws;
    short* wf   = (short*)(ws + WF_OFF);
    float* bias = ws + BIAS_OFF;
    short* yb0  = (short*)(ws + Y0_OFF);
    short* yb1  = (short*)(ws + Y1_OFF);

    prep_wb<<<(NCH * 6 * 64 + 255) / 256, 256, 0, stream>>>(pw, lsc, wf);
    prep_bias<<<COUT, 64, 0, stream>>>(pw, lbi, bias);
    conv_mfma<<<dim3(PIX / 64, B_, 2), 512, 0, stream>>>(x, wf, yb0, yb1);
    finalize<<<B_ * COUT, 256, 0, stream>>>(x, pad_hv, idt, yb0, yb1, bias, alpha, out);
}